// Round 2
// baseline (8063.186 us; speedup 1.0000x reference)
//
#include <hip/hip_runtime.h>
#include <hip/hip_bf16.h>

#define Bsz   2048
#define Tsz   32
#define Zsz   128
#define Hsz   512
#define Msz   256
#define Nsz   10
#define KDIM  896      // 128 (z) + 256 (read_vec) + 512 (h)
#define NGATE 2048
#define NHEAD 1040
#define NHEADP 1152    // padded to 9*128

__device__ __forceinline__ float sigmoidf_(float x) { return 1.f / (1.f + expf(-x)); }
__device__ __forceinline__ float softplusf_(float x) { return x > 20.f ? x : log1pf(expf(x)); }

__device__ __forceinline__ float wave_sum(float v) {
#pragma unroll
    for (int m = 32; m >= 1; m >>= 1) v += __shfl_xor(v, m, 64);
    return v;
}

// ---------------- prologue kernels ----------------

// LayerNorm over TIME axis (ddof=1, two-pass), fp32 out. t=32 plane = 0.
__global__ __launch_bounds__(256) void k_lnorm(
    const float* __restrict__ z_seq, const float* __restrict__ gamma,
    const float* __restrict__ beta, float* __restrict__ znorm)
{
    int idx = blockIdx.x * 256 + threadIdx.x;
    if (idx >= Bsz * Zsz) return;
    int b = idx >> 7, zi = idx & 127;
    const float* p = z_seq + (size_t)b * Tsz * Zsz + zi;
    float v[32];
    float s = 0.f;
#pragma unroll
    for (int t = 0; t < Tsz; t++) { v[t] = p[t * Zsz]; s += v[t]; }
    float mu = s * (1.f / 32.f);
    float ss = 0.f;
#pragma unroll
    for (int t = 0; t < Tsz; t++) { float d = v[t] - mu; ss += d * d; }
    float rs = rsqrtf(ss * (1.f / 31.f) + 1e-8f);
    float ga = gamma[zi], be = beta[zi];
#pragma unroll
    for (int t = 0; t < Tsz; t++) {
        znorm[((size_t)t * Bsz + b) * Zsz + zi] = (v[t] - mu) * rs * ga + be;
    }
    znorm[((size_t)Tsz * Bsz + b) * Zsz + zi] = 0.f;
}

// Wcat[n][k], n = 4*j + g  ->  W row r = g*512 + j  (gate-interleaved for fused epilogue)
__global__ __launch_bounds__(256) void k_prep_wcat(
    const float* __restrict__ W_ih, const float* __restrict__ W_hh,
    const float* __restrict__ b_ih, const float* __restrict__ b_hh,
    float* __restrict__ Wt, float* __restrict__ bcat)
{
    int idx = blockIdx.x * 256 + threadIdx.x;
    if (idx >= NGATE * KDIM) return;
    int n = idx / KDIM, k = idx % KDIM;
    int j = n >> 2, g = n & 3;
    int r = g * Hsz + j;
    float v = (k < 384) ? W_ih[(size_t)r * 384 + k] : W_hh[(size_t)r * Hsz + (k - 384)];
    Wt[idx] = v;
    if (k == 0) bcat[n] = b_ih[r] + b_hh[r];
}

struct HeadP { const float* W[13]; const float* b[13]; };

__global__ __launch_bounds__(256) void k_prep_heads(
    HeadP hp, float* __restrict__ Wt, float* __restrict__ bh)
{
    int idx = blockIdx.x * 256 + threadIdx.x;
    if (idx >= NHEADP * Hsz) return;
    int n = idx / Hsz, k = idx % Hsz;
    if (n >= NHEAD) { Wt[idx] = 0.f; if (k == 0) bh[n] = 0.f; return; }
    const int offs[14] = {0,256,512,768,1024,1028,1029,1030,1031,1032,1035,1038,1039,1040};
    int h = 0;
    while (n >= offs[h + 1]) h++;
    int local = n - offs[h];
    Wt[idx] = hp.W[h][(size_t)local * Hsz + k];
    if (k == 0) bh[n] = hp.b[h][local];
}

__global__ __launch_bounds__(256) void k_init(
    float* __restrict__ rvbuf, float* __restrict__ hA,
    float* __restrict__ cbuf, float* __restrict__ w_read, float* __restrict__ w_write,
    float* __restrict__ mem, const float* __restrict__ memory_init)
{
    int tid = blockIdx.x * blockDim.x + threadIdx.x;
    int stride = gridDim.x * blockDim.x;
    for (int i = tid; i < Bsz * Msz; i += stride) rvbuf[i] = 0.f;
    for (int i = tid; i < Bsz * Hsz; i += stride) { hA[i] = 0.f; cbuf[i] = 0.f; }
    for (int i = tid; i < Bsz * Nsz; i += stride) { w_read[i] = 0.f; w_write[i] = 0.f; }
    for (int i = tid; i < Bsz * Nsz * Msz; i += stride) mem[i] = memory_init[i % (Nsz * Msz)];
}

// ---------------- fp32 SGEMM per-step kernels ----------------
// 128x128 tile, 256 threads, 8x8 micro (rows mt*4..+3 and +64; cols nt*4..+3 and +64),
// K_STEP=8, LDS [k][m] layout, register-prefetch + double buffer.

// gates GEMM (M=2048, N=2048, K=896) + fused LSTM epilogue
__global__ __launch_bounds__(256) void k_gates(
    const float* __restrict__ zplane,  // B x 128 (this t)
    const float* __restrict__ rvbuf,   // B x 256
    const float* __restrict__ hin,     // B x 512
    const float* __restrict__ Wt,      // 2048 x 896 (n = 4j+g)
    const float* __restrict__ bcat,    // 2048
    float* __restrict__ cbuf,          // B x 512
    float* __restrict__ hout)          // B x 512
{
    __shared__ float As[2][8][128];
    __shared__ float Bs[2][8][128];
    const int tid = threadIdx.x;
    const int bm = blockIdx.x, bn = blockIdx.y;
    const int mt = tid & 15, nt = tid >> 4;
    const int ar = tid >> 1, kq = tid & 1;
    const int grow = bm * 128 + ar;
    const int nrow = bn * 128 + ar;

    float acc[8][8];
#pragma unroll
    for (int i = 0; i < 8; i++)
#pragma unroll
        for (int j = 0; j < 8; j++) acc[i][j] = 0.f;

    auto loadA = [&](int k0) -> float4 {
        int k = k0 + kq * 4;
        const float* src;
        if (k < 128)      src = zplane + (size_t)grow * Zsz + k;
        else if (k < 384) src = rvbuf + (size_t)grow * Msz + (k - 128);
        else              src = hin + (size_t)grow * Hsz + (k - 384);
        return *reinterpret_cast<const float4*>(src);
    };
    auto loadB = [&](int k0) -> float4 {
        return *reinterpret_cast<const float4*>(Wt + (size_t)nrow * KDIM + k0 + kq * 4);
    };
    auto store = [&](int buf, float4 a, float4 b) {
        As[buf][kq * 4 + 0][ar] = a.x; As[buf][kq * 4 + 1][ar] = a.y;
        As[buf][kq * 4 + 2][ar] = a.z; As[buf][kq * 4 + 3][ar] = a.w;
        Bs[buf][kq * 4 + 0][ar] = b.x; Bs[buf][kq * 4 + 1][ar] = b.y;
        Bs[buf][kq * 4 + 2][ar] = b.z; Bs[buf][kq * 4 + 3][ar] = b.w;
    };

    {
        float4 av = loadA(0), bv = loadB(0);
        store(0, av, bv);
    }
    __syncthreads();
    int cur = 0;
    const int NT = KDIM / 8;
    for (int kt = 0; kt < NT; ++kt) {
        float4 av2, bv2;
        if (kt + 1 < NT) { av2 = loadA((kt + 1) * 8); bv2 = loadB((kt + 1) * 8); }
#pragma unroll
        for (int k = 0; k < 8; ++k) {
            float4 a0 = *reinterpret_cast<const float4*>(&As[cur][k][mt * 4]);
            float4 a1 = *reinterpret_cast<const float4*>(&As[cur][k][64 + mt * 4]);
            float4 b0 = *reinterpret_cast<const float4*>(&Bs[cur][k][nt * 4]);
            float4 b1 = *reinterpret_cast<const float4*>(&Bs[cur][k][64 + nt * 4]);
            float a_[8] = {a0.x,a0.y,a0.z,a0.w,a1.x,a1.y,a1.z,a1.w};
            float b_[8] = {b0.x,b0.y,b0.z,b0.w,b1.x,b1.y,b1.z,b1.w};
#pragma unroll
            for (int r = 0; r < 8; r++)
#pragma unroll
                for (int c = 0; c < 8; c++) acc[r][c] = fmaf(a_[r], b_[c], acc[r][c]);
        }
        if (kt + 1 < NT) {
            store(cur ^ 1, av2, bv2);
            __syncthreads();
            cur ^= 1;
        }
    }

    // LSTM epilogue: cols {nt*4..+3} -> unit j1=bn*32+nt gates 0..3; {+64} -> j2=j1+16
    const int j1 = bn * 32 + nt;
    const int j2 = j1 + 16;
    const float4 bc1 = *reinterpret_cast<const float4*>(&bcat[4 * j1]);
    const float4 bc2 = *reinterpret_cast<const float4*>(&bcat[4 * j2]);
#pragma unroll
    for (int half = 0; half < 2; ++half) {
#pragma unroll
        for (int rr = 0; rr < 4; ++rr) {
            int r = half * 4 + rr;
            int m = bm * 128 + half * 64 + mt * 4 + rr;
            {
                float iv = acc[r][0] + bc1.x;
                float fv = acc[r][1] + bc1.y;
                float gv = acc[r][2] + bc1.z;
                float ov = acc[r][3] + bc1.w;
                size_t ci = (size_t)m * Hsz + j1;
                float co = cbuf[ci];
                float cn = sigmoidf_(fv) * co + sigmoidf_(iv) * tanhf(gv);
                cbuf[ci] = cn;
                hout[ci] = sigmoidf_(ov) * tanhf(cn);
            }
            {
                float iv = acc[r][4] + bc2.x;
                float fv = acc[r][5] + bc2.y;
                float gv = acc[r][6] + bc2.z;
                float ov = acc[r][7] + bc2.w;
                size_t ci = (size_t)m * Hsz + j2;
                float co = cbuf[ci];
                float cn = sigmoidf_(fv) * co + sigmoidf_(iv) * tanhf(gv);
                cbuf[ci] = cn;
                hout[ci] = sigmoidf_(ov) * tanhf(cn);
            }
        }
    }
}

// heads GEMM (M=2048, N=1040 padded 1152, K=512) -> headbuf fp32
__global__ __launch_bounds__(256) void k_heads(
    const float* __restrict__ hbuf,  // B x 512
    const float* __restrict__ Wt,    // 1152 x 512 (padded, zero rows >=1040)
    const float* __restrict__ bh,    // 1152
    float* __restrict__ headbuf)     // B x 1040
{
    __shared__ float As[2][8][128];
    __shared__ float Bs[2][8][128];
    const int tid = threadIdx.x;
    const int bm = blockIdx.x, bn = blockIdx.y;
    const int mt = tid & 15, nt = tid >> 4;
    const int ar = tid >> 1, kq = tid & 1;
    const int grow = bm * 128 + ar;
    const int nrow = bn * 128 + ar;

    float acc[8][8];
#pragma unroll
    for (int i = 0; i < 8; i++)
#pragma unroll
        for (int j = 0; j < 8; j++) acc[i][j] = 0.f;

    auto loadA = [&](int k0) -> float4 {
        return *reinterpret_cast<const float4*>(hbuf + (size_t)grow * Hsz + k0 + kq * 4);
    };
    auto loadB = [&](int k0) -> float4 {
        return *reinterpret_cast<const float4*>(Wt + (size_t)nrow * Hsz + k0 + kq * 4);
    };
    auto store = [&](int buf, float4 a, float4 b) {
        As[buf][kq * 4 + 0][ar] = a.x; As[buf][kq * 4 + 1][ar] = a.y;
        As[buf][kq * 4 + 2][ar] = a.z; As[buf][kq * 4 + 3][ar] = a.w;
        Bs[buf][kq * 4 + 0][ar] = b.x; Bs[buf][kq * 4 + 1][ar] = b.y;
        Bs[buf][kq * 4 + 2][ar] = b.z; Bs[buf][kq * 4 + 3][ar] = b.w;
    };

    {
        float4 av = loadA(0), bv = loadB(0);
        store(0, av, bv);
    }
    __syncthreads();
    int cur = 0;
    const int NT = Hsz / 8;
    for (int kt = 0; kt < NT; ++kt) {
        float4 av2, bv2;
        if (kt + 1 < NT) { av2 = loadA((kt + 1) * 8); bv2 = loadB((kt + 1) * 8); }
#pragma unroll
        for (int k = 0; k < 8; ++k) {
            float4 a0 = *reinterpret_cast<const float4*>(&As[cur][k][mt * 4]);
            float4 a1 = *reinterpret_cast<const float4*>(&As[cur][k][64 + mt * 4]);
            float4 b0 = *reinterpret_cast<const float4*>(&Bs[cur][k][nt * 4]);
            float4 b1 = *reinterpret_cast<const float4*>(&Bs[cur][k][64 + nt * 4]);
            float a_[8] = {a0.x,a0.y,a0.z,a0.w,a1.x,a1.y,a1.z,a1.w};
            float b_[8] = {b0.x,b0.y,b0.z,b0.w,b1.x,b1.y,b1.z,b1.w};
#pragma unroll
            for (int r = 0; r < 8; r++)
#pragma unroll
                for (int c = 0; c < 8; c++) acc[r][c] = fmaf(a_[r], b_[c], acc[r][c]);
        }
        if (kt + 1 < NT) {
            store(cur ^ 1, av2, bv2);
            __syncthreads();
            cur ^= 1;
        }
    }

    const int n0 = bn * 128;
#pragma unroll
    for (int half = 0; half < 2; ++half) {
#pragma unroll
        for (int rr = 0; rr < 4; ++rr) {
            int r = half * 4 + rr;
            int m = bm * 128 + half * 64 + mt * 4 + rr;
#pragma unroll
            for (int ch = 0; ch < 2; ++ch) {
                int nb = n0 + ch * 64 + nt * 4;
#pragma unroll
                for (int cc = 0; cc < 4; ++cc) {
                    int n = nb + cc;
                    if (n < NHEAD)
                        headbuf[(size_t)m * NHEAD + n] = acc[r][ch * 4 + cc] + bh[n];
                }
            }
        }
    }
}

// ---------------- addressing / memory update (1 wave per batch row) ----------------

__device__ inline void compute_address(
    const float dot[10], const float mn[10], float kn, float strength, float gate,
    const float sh[3], float sharp, const float* __restrict__ wprev, bool interp,
    float out[10])
{
    float w[10];
    float mx = -1e30f;
#pragma unroll
    for (int n = 0; n < 10; n++) {
        w[n] = strength * (dot[n] / (kn * mn[n]));
        mx = fmaxf(mx, w[n]);
    }
    float s = 0.f;
#pragma unroll
    for (int n = 0; n < 10; n++) { w[n] = expf(w[n] - mx); s += w[n]; }
    float inv = 1.f / s;
#pragma unroll
    for (int n = 0; n < 10; n++) w[n] *= inv;
    if (interp) {
#pragma unroll
        for (int n = 0; n < 10; n++) w[n] = gate * w[n] + (1.f - gate) * wprev[n];
    }
    float w2[10];
#pragma unroll
    for (int n = 0; n < 10; n++) {
        int np1 = (n + 1) % 10, nm1 = (n + 9) % 10;
        w2[n] = sh[0] * w[np1] + sh[1] * w[n] + sh[2] * w[nm1];
    }
    float ssum = 0.f;
#pragma unroll
    for (int n = 0; n < 10; n++) { w2[n] = powf(w2[n], sharp); ssum += w2[n]; }
    float rinv = 1.f / ssum;
#pragma unroll
    for (int n = 0; n < 10; n++) out[n] = w2[n] * rinv;
}

__global__ __launch_bounds__(64) void k_addr(
    const float* __restrict__ headbuf,   // B x 1040
    float* __restrict__ mem,             // B x 10 x 256
    float* __restrict__ w_read, float* __restrict__ w_write,  // B x 10
    float* __restrict__ rvbuf,           // B x 256
    float* __restrict__ d_out,           // 8192 y + 2048 argmax
    int t)
{
    const int b = blockIdx.x;
    const int lane = threadIdx.x;
    const float eps = 1e-8f;
    const float* hb = headbuf + (size_t)b * NHEAD;

    float rk[4], wk[4], er[4], ad[4], mreg[10][4];
#pragma unroll
    for (int q = 0; q < 4; q++) {
        int m = lane + 64 * q;
        rk[q] = tanhf(hb[m]);
        wk[q] = tanhf(hb[256 + m]);
        er[q] = sigmoidf_(hb[512 + m]);
        ad[q] = tanhf(hb[768 + m]);
    }
    float* memb = mem + (size_t)b * Nsz * Msz;

    float knr2 = 0.f, knw2 = 0.f;
#pragma unroll
    for (int q = 0; q < 4; q++) { knr2 += rk[q] * rk[q]; knw2 += wk[q] * wk[q]; }
    float knr = fmaxf(sqrtf(wave_sum(knr2)), eps);
    float knw = fmaxf(sqrtf(wave_sum(knw2)), eps);

    float dotr[10], dotw[10], mn[10];
#pragma unroll
    for (int n = 0; n < 10; n++) {
        float dr = 0.f, dw = 0.f, m2 = 0.f;
#pragma unroll
        for (int q = 0; q < 4; q++) {
            float mv = memb[n * Msz + lane + 64 * q];
            mreg[n][q] = mv;
            dr += rk[q] * mv; dw += wk[q] * mv; m2 += mv * mv;
        }
        dotr[n] = wave_sum(dr);
        dotw[n] = wave_sum(dw);
        mn[n] = fmaxf(sqrtf(wave_sum(m2)), eps);
    }

    float rks = softplusf_(hb[1028]);
    float wks = softplusf_(hb[1029]);
    float rig = sigmoidf_(hb[1030]);
    float wig = sigmoidf_(hb[1031]);
    float rsh[3], wsh[3];
    {
        float a0 = hb[1032], a1 = hb[1033], a2 = hb[1034];
        float mx = fmaxf(a0, fmaxf(a1, a2));
        float e0 = expf(a0 - mx), e1 = expf(a1 - mx), e2 = expf(a2 - mx);
        float inv = 1.f / (e0 + e1 + e2);
        rsh[0] = e0 * inv; rsh[1] = e1 * inv; rsh[2] = e2 * inv;
        a0 = hb[1035]; a1 = hb[1036]; a2 = hb[1037];
        mx = fmaxf(a0, fmaxf(a1, a2));
        e0 = expf(a0 - mx); e1 = expf(a1 - mx); e2 = expf(a2 - mx);
        inv = 1.f / (e0 + e1 + e2);
        wsh[0] = e0 * inv; wsh[1] = e1 * inv; wsh[2] = e2 * inv;
    }
    float rshp = softplusf_(hb[1038]) + 1.f;
    float wshp = softplusf_(hb[1039]) + 1.f;

    float wfr[10], wfw[10];
    compute_address(dotr, mn, knr, rks, rig, rsh, rshp, w_read + (size_t)b * Nsz, t > 1, wfr);
    compute_address(dotw, mn, knw, wks, wig, wsh, wshp, w_write + (size_t)b * Nsz, t > 0, wfw);

    // read_vec from OLD mem
#pragma unroll
    for (int q = 0; q < 4; q++) {
        float rv = 0.f;
#pragma unroll
        for (int n = 0; n < 10; n++) rv += mreg[n][q] * wfr[n];
        if (t == 0) rv = 0.f;
        rvbuf[(size_t)b * Msz + lane + 64 * q] = rv;
    }
    // state weight vectors
    if (lane < 10) {
        if (t != 0) w_read[(size_t)b * Nsz + lane] = wfr[lane];
        w_write[(size_t)b * Nsz + lane] = wfw[lane];
    }
    // memory update (write weights = new w_write)
#pragma unroll
    for (int n = 0; n < 10; n++) {
        float wwn = wfw[n];
#pragma unroll
        for (int q = 0; q < 4; q++) {
            int m = lane + 64 * q;
            memb[n * Msz + m] = mreg[n][q] * (1.f - er[q] * wwn) + ad[q] * wwn;
        }
    }
    // final output at t == 32
    if (t == Tsz) {
        if (lane < 4) d_out[(size_t)b * 4 + lane] = hb[1024 + lane];
        if (lane == 0) {
            float y0 = hb[1024], y1 = hb[1025], y2 = hb[1026], y3 = hb[1027];
            int idx = 0; float best = y0;
            if (y1 > best) { best = y1; idx = 1; }
            if (y2 > best) { best = y2; idx = 2; }
            if (y3 > best) { best = y3; idx = 3; }
            d_out[Bsz * 4 + b] = (float)idx;
        }
    }
}

// ---------------- host ----------------

extern "C" void kernel_launch(void* const* d_in, const int* in_sizes, int n_in,
                              void* d_out, int out_size, void* d_ws, size_t ws_size,
                              hipStream_t stream) {
    const float* z_seq = (const float*)d_in[0];
    const float* W_ih  = (const float*)d_in[1];
    const float* W_hh  = (const float*)d_in[2];
    const float* b_ih  = (const float*)d_in[3];
    const float* b_hh  = (const float*)d_in[4];
    const float* memory_init = (const float*)d_in[31];
    const float* gamma = (const float*)d_in[32];
    const float* beta  = (const float*)d_in[33];

    HeadP hp;
    for (int i = 0; i < 13; i++) {
        hp.W[i] = (const float*)d_in[5 + 2 * i];
        hp.b[i] = (const float*)d_in[6 + 2 * i];
    }

    char* ws = (char*)d_ws;
    size_t off = 0;
    auto alloc = [&](size_t bytes) -> void* {
        off = (off + 255) & ~(size_t)255;
        void* p = ws + off;
        off += bytes;
        return p;
    };
    float* znorm   = (float*)alloc((size_t)33 * Bsz * Zsz * 4);
    float* rvbuf   = (float*)alloc((size_t)Bsz * Msz * 4);
    float* hA      = (float*)alloc((size_t)Bsz * Hsz * 4);
    float* hB      = (float*)alloc((size_t)Bsz * Hsz * 4);
    float* cbuf    = (float*)alloc((size_t)Bsz * Hsz * 4);
    float* mem     = (float*)alloc((size_t)Bsz * Nsz * Msz * 4);
    float* w_read  = (float*)alloc((size_t)Bsz * Nsz * 4);
    float* w_write = (float*)alloc((size_t)Bsz * Nsz * 4);
    float* headbuf = (float*)alloc((size_t)Bsz * NHEAD * 4);
    float* Wcat    = (float*)alloc((size_t)NGATE * KDIM * 4);
    float* bcat    = (float*)alloc((size_t)NGATE * 4);
    float* Whead   = (float*)alloc((size_t)NHEADP * Hsz * 4);
    float* bhead   = (float*)alloc((size_t)NHEADP * 4);

    // prologue
    k_prep_wcat<<<(NGATE * KDIM + 255) / 256, 256, 0, stream>>>(W_ih, W_hh, b_ih, b_hh, Wcat, bcat);
    k_prep_heads<<<(NHEADP * Hsz + 255) / 256, 256, 0, stream>>>(hp, Whead, bhead);
    k_lnorm<<<(Bsz * Zsz + 255) / 256, 256, 0, stream>>>(z_seq, gamma, beta, znorm);
    k_init<<<2048, 256, 0, stream>>>(rvbuf, hA, cbuf, w_read, w_write, mem, memory_init);

    float* out_f = (float*)d_out;
    for (int t = 0; t <= Tsz; t++) {
        const float* hin = (t & 1) ? hB : hA;
        float* hout      = (t & 1) ? hA : hB;
        k_gates<<<dim3(Bsz / 128, NGATE / 128), 256, 0, stream>>>(
            znorm + (size_t)t * Bsz * Zsz, rvbuf, hin, Wcat, bcat, cbuf, hout);
        k_heads<<<dim3(Bsz / 128, NHEADP / 128), 256, 0, stream>>>(
            hout, Whead, bhead, headbuf);
        k_addr<<<Bsz, 64, 0, stream>>>(headbuf, mem, w_read, w_write, rvbuf, out_f, t);
    }
}